// Round 1
// baseline (254.944 us; speedup 1.0000x reference)
//
#include <hip/hip_runtime.h>

#define BB 8
#define TT 256
#define DD 512
#define AA 512

// ---- fast branch-free tanh: 1 - 2/(1+exp(2x)) ----
__device__ __forceinline__ float fast_tanh(float x) {
    float e = __builtin_amdgcn_exp2f(x * 2.8853900817779268f); // exp(2x)
    float r = __builtin_amdgcn_rcpf(1.0f + e);
    return fmaf(-2.0f, r, 1.0f);
}

#define LOG2E 1.4426950408889634f

// ---------------- K0: ii = final_state @ W_ii + b_ii ----------------
__global__ __launch_bounds__(256) void k0_ii(const float* __restrict__ fs_g,
                                             const float* __restrict__ Wii,
                                             const float* __restrict__ bii,
                                             float* __restrict__ ii) {
    int b = blockIdx.x, tid = threadIdx.x;
    __shared__ float fs[DD];
    fs[tid]       = fs_g[b * DD + tid];
    fs[tid + 256] = fs_g[b * DD + tid + 256];
    __syncthreads();
    for (int a0 = tid; a0 < AA; a0 += 256) {
        float acc = bii[a0];
        #pragma unroll 4
        for (int d = 0; d < DD; ++d)
            acc = fmaf(fs[d], Wii[d * AA + a0], acc);
        ii[b * AA + a0] = acc;
    }
}

// ---------------- K1: tiled GEMM over SO[2048,512] ----------------
// mode 0: sh = SO@W_sh + b_sh  -> stored TRANSPOSED per batch: shT[b][a][t]
// mode 1: si = SO@W_si + b_si  -> stored [b*T+t][a]
// mode 2: ih = SO@W_ih + b_ih  -> fused: ipart[nblk][m] = sum_n iv[n]*tanh(ih+ii)
#define TS 64
#define KS 16
#define LPAD 72

__global__ __launch_bounds__(256) void k1_gemm(
    const float* __restrict__ SO,
    const float* __restrict__ Wsh, const float* __restrict__ bsh,
    const float* __restrict__ Wsi, const float* __restrict__ bsi,
    const float* __restrict__ Wih, const float* __restrict__ bih,
    const float* __restrict__ ii, const float* __restrict__ iv,
    float* __restrict__ shT, float* __restrict__ si_o, float* __restrict__ ipart) {
    const int mode = blockIdx.z;
    const float* W;
    const float* bias;
    if (mode == 0)      { W = Wsh; bias = bsh; }
    else if (mode == 1) { W = Wsi; bias = bsi; }
    else                { W = Wih; bias = bih; }

    const int m0 = blockIdx.x * TS;
    const int n0 = blockIdx.y * TS;
    const int tid = threadIdx.x;
    const int tx = tid & 15, ty = tid >> 4;

    __shared__ __align__(16) float As[KS][LPAD];
    __shared__ __align__(16) float Bs[KS][LPAD];
    __shared__ __align__(16) float Cs[TS][LPAD];

    float acc[4][4] = {};

    const int arow = tid >> 2;        // 0..63
    const int akc  = (tid & 3) * 4;   // 0,4,8,12
    const int brw  = tid >> 4;        // 0..15
    const int bnc  = (tid & 15) * 4;  // 0..60

    for (int k0 = 0; k0 < DD; k0 += KS) {
        float4 av = *reinterpret_cast<const float4*>(&SO[(m0 + arow) * DD + k0 + akc]);
        As[akc + 0][arow] = av.x;
        As[akc + 1][arow] = av.y;
        As[akc + 2][arow] = av.z;
        As[akc + 3][arow] = av.w;
        float4 bv = *reinterpret_cast<const float4*>(&W[(k0 + brw) * AA + n0 + bnc]);
        *reinterpret_cast<float4*>(&Bs[brw][bnc]) = bv;
        __syncthreads();
        #pragma unroll
        for (int kk = 0; kk < KS; ++kk) {
            float4 a4 = *reinterpret_cast<const float4*>(&As[kk][ty * 4]);
            float4 b4 = *reinterpret_cast<const float4*>(&Bs[kk][tx * 4]);
            float av_[4] = {a4.x, a4.y, a4.z, a4.w};
            float bv_[4] = {b4.x, b4.y, b4.z, b4.w};
            #pragma unroll
            for (int i = 0; i < 4; ++i)
                #pragma unroll
                for (int j = 0; j < 4; ++j)
                    acc[i][j] = fmaf(av_[i], bv_[j], acc[i][j]);
        }
        __syncthreads();
    }

    if (mode == 1) {
        #pragma unroll
        for (int i = 0; i < 4; ++i) {
            int m = m0 + ty * 4 + i;
            float4 v;
            v.x = acc[i][0] + bias[n0 + tx * 4 + 0];
            v.y = acc[i][1] + bias[n0 + tx * 4 + 1];
            v.z = acc[i][2] + bias[n0 + tx * 4 + 2];
            v.w = acc[i][3] + bias[n0 + tx * 4 + 3];
            *reinterpret_cast<float4*>(&si_o[m * AA + n0 + tx * 4]) = v;
        }
    } else if (mode == 0) {
        // stage transposed in LDS, then coalesced write to shT[b][n][t]
        #pragma unroll
        for (int i = 0; i < 4; ++i)
            #pragma unroll
            for (int j = 0; j < 4; ++j)
                Cs[tx * 4 + j][ty * 4 + i] = acc[i][j] + bias[n0 + tx * 4 + j];
        __syncthreads();
        int row = tid >> 2, part = tid & 3;
        int bb = m0 >> 8;  // tile never crosses batch (256 % 64 == 0)
        int tstart = (m0 & 255) + part * 16;
        float* dst = &shT[bb * (AA * TT) + (n0 + row) * TT + tstart];
        #pragma unroll
        for (int q = 0; q < 4; ++q) {
            float4 v = *reinterpret_cast<const float4*>(&Cs[row][part * 16 + q * 4]);
            *reinterpret_cast<float4*>(&dst[q * 4]) = v;
        }
    } else {
        // intent: per-row partial dot of iv * tanh(ih + ii)
        int bb = m0 >> 8;
        #pragma unroll
        for (int i = 0; i < 4; ++i) {
            float p = 0.f;
            #pragma unroll
            for (int j = 0; j < 4; ++j) {
                int n = n0 + tx * 4 + j;
                float x = acc[i][j] + bias[n] + ii[bb * AA + n];
                p = fmaf(iv[n], fast_tanh(x), p);
            }
            Cs[ty * 4 + i][tx] = p;
        }
        __syncthreads();
        if (tid < 64) {
            float s = 0.f;
            #pragma unroll
            for (int k = 0; k < 16; ++k) s += Cs[tid][k];
            ipart[blockIdx.y * (BB * TT) + m0 + tid] = s;  // deterministic (no atomics)
        }
    }
}

// ---------------- K2: intent softmax + c_intent ----------------
__global__ __launch_bounds__(256) void k2_intent(const float* __restrict__ SO,
                                                 const float* __restrict__ ipart,
                                                 float* __restrict__ out_cint) {
    int b = blockIdx.x, tid = threadIdx.x;
    __shared__ float red[256];
    __shared__ float wl[256];
    float s = 0.f;
    #pragma unroll
    for (int nb = 0; nb < 8; ++nb) s += ipart[nb * (BB * TT) + b * TT + tid];
    red[tid] = s;
    __syncthreads();
    for (int off = 128; off > 0; off >>= 1) {
        if (tid < off) red[tid] = fmaxf(red[tid], red[tid + off]);
        __syncthreads();
    }
    float m = red[0];
    __syncthreads();
    float e = __builtin_amdgcn_exp2f((s - m) * LOG2E);
    red[tid] = e;
    __syncthreads();
    for (int off = 128; off > 0; off >>= 1) {
        if (tid < off) red[tid] += red[tid + off];
        __syncthreads();
    }
    float w = e * __builtin_amdgcn_rcpf(red[0]);
    wl[tid] = w;
    __syncthreads();
    #pragma unroll
    for (int half = 0; half < 2; ++half) {
        int d = tid + half * 256;
        float acc = 0.f;
        #pragma unroll 4
        for (int s2 = 0; s2 < TT; ++s2)
            acc = fmaf(wl[s2], SO[(b * TT + s2) * DD + d], acc);
        out_cint[b * DD + d] = acc;
    }
}

// ---------------- K3: fused slot score + softmax + PV ----------------
// One block handles (b, t0..t0+3); thread tid = key index s.
__global__ __launch_bounds__(256) void k3_slot(const float* __restrict__ SO,
                                               const float* __restrict__ shT,
                                               const float* __restrict__ si,
                                               const float* __restrict__ sv_g,
                                               float* __restrict__ out_cslot) {
    const int bid = blockIdx.x;
    const int b  = bid & 7;   // XCD-affine: all blocks of batch b land on one XCD
    const int tg = bid >> 3;  // 0..63
    const int t0 = tg * 4;
    const int tid = threadIdx.x;

    __shared__ float sil[4][AA];
    __shared__ float sv[AA];
    __shared__ float wl[4][TT];
    __shared__ float red[256];

    sv[tid]       = sv_g[tid];
    sv[tid + 256] = sv_g[tid + 256];
    #pragma unroll
    for (int q = 0; q < 4; ++q) {
        sil[q][tid]       = si[(b * TT + t0 + q) * AA + tid];
        sil[q][tid + 256] = si[(b * TT + t0 + q) * AA + tid + 256];
    }
    __syncthreads();

    const float* sb = &shT[b * AA * TT];
    float a0 = 0.f, a1 = 0.f, a2 = 0.f, a3 = 0.f;
    #pragma unroll 4
    for (int a = 0; a < AA; ++a) {
        float h = sb[a * TT + tid];  // coalesced along s
        float v = sv[a];
        a0 = fmaf(v, fast_tanh(h + sil[0][a]), a0);
        a1 = fmaf(v, fast_tanh(h + sil[1][a]), a1);
        a2 = fmaf(v, fast_tanh(h + sil[2][a]), a2);
        a3 = fmaf(v, fast_tanh(h + sil[3][a]), a3);
    }

    float sc[4] = {a0, a1, a2, a3};
    #pragma unroll
    for (int q = 0; q < 4; ++q) {
        red[tid] = sc[q];
        __syncthreads();
        for (int off = 128; off > 0; off >>= 1) {
            if (tid < off) red[tid] = fmaxf(red[tid], red[tid + off]);
            __syncthreads();
        }
        float m = red[0];
        __syncthreads();
        float e = __builtin_amdgcn_exp2f((sc[q] - m) * LOG2E);
        red[tid] = e;
        __syncthreads();
        for (int off = 128; off > 0; off >>= 1) {
            if (tid < off) red[tid] += red[tid + off];
            __syncthreads();
        }
        wl[q][tid] = e * __builtin_amdgcn_rcpf(red[0]);
        __syncthreads();
    }

    // PV: c_slot[b][t0+q][d] = sum_s wl[q][s] * SO[b][s][d]
    #pragma unroll
    for (int half = 0; half < 2; ++half) {
        int d = tid + half * 256;
        float c0 = 0.f, c1 = 0.f, c2 = 0.f, c3 = 0.f;
        #pragma unroll 4
        for (int s2 = 0; s2 < TT; ++s2) {
            float so = SO[(b * TT + s2) * DD + d];
            c0 = fmaf(wl[0][s2], so, c0);
            c1 = fmaf(wl[1][s2], so, c1);
            c2 = fmaf(wl[2][s2], so, c2);
            c3 = fmaf(wl[3][s2], so, c3);
        }
        out_cslot[(b * TT + t0 + 0) * DD + d] = c0;
        out_cslot[(b * TT + t0 + 1) * DD + d] = c1;
        out_cslot[(b * TT + t0 + 2) * DD + d] = c2;
        out_cslot[(b * TT + t0 + 3) * DD + d] = c3;
    }
}

extern "C" void kernel_launch(void* const* d_in, const int* in_sizes, int n_in,
                              void* d_out, int out_size, void* d_ws, size_t ws_size,
                              hipStream_t stream) {
    const float* SO  = (const float*)d_in[0];
    const float* FS  = (const float*)d_in[1];
    const float* IV  = (const float*)d_in[2];
    const float* Wih = (const float*)d_in[3];
    const float* bih = (const float*)d_in[4];
    const float* Wii = (const float*)d_in[5];
    const float* bii = (const float*)d_in[6];
    const float* SV  = (const float*)d_in[7];
    const float* Wsh = (const float*)d_in[8];
    const float* bsh = (const float*)d_in[9];
    const float* Wsi = (const float*)d_in[10];
    const float* bsi = (const float*)d_in[11];

    float* ws   = (float*)d_ws;
    float* shT  = ws;                 // [B][A][T]  1,048,576 floats
    float* si   = ws + 1048576;       // [B*T][A]   1,048,576 floats
    float* ii   = ws + 2097152;       // [B][A]     4,096 floats
    float* ipart= ws + 2101248;       // [8][B*T]   16,384 floats

    float* out_cslot = (float*)d_out;             // [B][T][D]
    float* out_cint  = out_cslot + BB * TT * DD;  // [B][D]

    k0_ii<<<BB, 256, 0, stream>>>(FS, Wii, bii, ii);
    k1_gemm<<<dim3(32, 8, 3), 256, 0, stream>>>(SO, Wsh, bsh, Wsi, bsi, Wih, bih,
                                                ii, IV, shT, si, ipart);
    k2_intent<<<BB, 256, 0, stream>>>(SO, ipart, out_cint);
    k3_slot<<<512, 256, 0, stream>>>(SO, shT, si, SV, out_cslot);
}

// Round 2
// 193.963 us; speedup vs baseline: 1.3144x; 1.3144x over previous
//
#include <hip/hip_runtime.h>

#define BB 8
#define TT 256
#define DD 512
#define AA 512

#define PS 2.8853900817779268f   // 2*log2(e)
#define LOG2E 1.4426950408889634f

typedef __attribute__((ext_vector_type(8))) short short8;
typedef __attribute__((ext_vector_type(4))) float f32x4;

// ---- fast branch-free tanh: 1 - 2/(1+exp2(2x*log2e)) ----
__device__ __forceinline__ float fast_tanh(float x) {
    float e = __builtin_amdgcn_exp2f(x * PS);
    float r = __builtin_amdgcn_rcpf(1.0f + e);
    return fmaf(-2.0f, r, 1.0f);
}

__device__ __forceinline__ ushort f2bf(float x) {
    uint u = __float_as_uint(x);
    uint r = (u + 0x7fffu + ((u >> 16) & 1u)) >> 16;  // RNE
    return (ushort)r;
}
__device__ __forceinline__ float bf2f(ushort h) {
    return __uint_as_float(((uint)h) << 16);
}

// ---------------- conv_A: SO[2048][512] f32 -> Ast bf16 [2048][1024] = [hi|lo] ----------------
__global__ __launch_bounds__(256) void conv_A(const float* __restrict__ SO,
                                              ushort* __restrict__ Ast) {
    int qid = blockIdx.x * 256 + threadIdx.x;  // 262144 quads
    int m = qid >> 7;
    int k4 = (qid & 127) * 4;
    float4 v = *reinterpret_cast<const float4*>(&SO[(size_t)m * 512 + k4]);
    ushort4 hi, lo;
    hi.x = f2bf(v.x); lo.x = f2bf(v.x - bf2f(hi.x));
    hi.y = f2bf(v.y); lo.y = f2bf(v.y - bf2f(hi.y));
    hi.z = f2bf(v.z); lo.z = f2bf(v.z - bf2f(hi.z));
    hi.w = f2bf(v.w); lo.w = f2bf(v.w - bf2f(hi.w));
    *reinterpret_cast<ushort4*>(&Ast[(size_t)m * 1024 + k4])       = hi;
    *reinterpret_cast<ushort4*>(&Ast[(size_t)m * 1024 + 512 + k4]) = lo;
}

// ---------------- conv_W: transpose-convert 3x W[512][512] -> Wt bf16 [1536][1024] = [hi|lo] ----------------
__global__ __launch_bounds__(256) void conv_W(const float* __restrict__ Wsh,
                                              const float* __restrict__ Wsi,
                                              const float* __restrict__ Wih,
                                              ushort* __restrict__ Wt) {
    const float* W = (blockIdx.z == 0) ? Wsh : (blockIdx.z == 1) ? Wsi : Wih;
    __shared__ float T[32][33];
    int tx = threadIdx.x & 31, ty = threadIdx.x >> 5;  // ty 0..7
    int k0 = blockIdx.x * 32, n0 = blockIdx.y * 32;
    #pragma unroll
    for (int r = 0; r < 4; ++r) {
        int kl = ty * 4 + r;
        T[kl][tx] = W[(size_t)(k0 + kl) * 512 + n0 + tx];
    }
    __syncthreads();
    size_t nbase = (size_t)blockIdx.z * 512 + n0;
    #pragma unroll
    for (int r = 0; r < 4; ++r) {
        int nl = ty * 4 + r;
        float v = T[tx][nl];
        ushort hi = f2bf(v);
        ushort lo = f2bf(v - bf2f(hi));
        Wt[(nbase + nl) * 1024 + k0 + tx]       = hi;
        Wt[(nbase + nl) * 1024 + 512 + k0 + tx] = lo;
    }
}

// ---------------- k0: ii = final_state @ W_ii + b_ii ----------------
__global__ __launch_bounds__(256) void k0_ii(const float* __restrict__ fs_g,
                                             const float* __restrict__ Wii,
                                             const float* __restrict__ bii,
                                             float* __restrict__ ii) {
    int b = blockIdx.x, tid = threadIdx.x;
    int a = blockIdx.y * 256 + tid;
    __shared__ float fs[DD];
    fs[tid]       = fs_g[b * DD + tid];
    fs[tid + 256] = fs_g[b * DD + tid + 256];
    __syncthreads();
    float acc = bii[a];
    #pragma unroll 8
    for (int d = 0; d < DD; ++d)
        acc = fmaf(fs[d], Wii[(size_t)d * AA + a], acc);
    ii[b * AA + a] = acc;
}

// ---------------- gemm_mfma: C[2048][1536] = Ast' x Wt', fused epilogues ----------------
// K = 1536 logical: [0,512)   -> A hi, W hi
//                   [512,1024)-> A lo, W hi
//                   [1024,1536)->A hi, W lo
// Ast [2048][1024] = [hi|lo]; Wt [1536][1024] = [hi|lo] (row = n, col = k)
// N regions: [0,512)=sh -> shT[b][a][t]*PS ; [512,1024)=si -> si2[m][n]*PS ;
//            [1024,1536)=ih -> ipart[slot][m] = partial sum iv*tanh(ih+ii+bih)
__global__ __launch_bounds__(256) void gemm_mfma(
    const ushort* __restrict__ Ast, const ushort* __restrict__ Wt,
    const float* __restrict__ bsh, const float* __restrict__ bsi,
    const float* __restrict__ bih,
    const float* __restrict__ ii, const float* __restrict__ iv,
    float* __restrict__ shT, float* __restrict__ si2, float* __restrict__ ipart) {
    __shared__ ushort Al[64 * 64];
    __shared__ ushort Bl[64 * 64];
    const int tid = threadIdx.x;
    const int wave = tid >> 6, lane = tid & 63;
    const int wr = wave >> 1, wc = wave & 1;
    const int m0 = blockIdx.x * 64;
    const int by = blockIdx.y;
    const int n0 = by * 64;
    const int r8 = lane >> 3, c8 = lane & 7;
    const int l15 = lane & 15, kb = lane >> 4;

    f32x4 acc[2][2] = {};

    const char* Ab = reinterpret_cast<const char*>(Ast);
    const char* Bb = reinterpret_cast<const char*>(Wt);
    char* AlB = reinterpret_cast<char*>(Al);
    char* BlB = reinterpret_cast<char*>(Bl);

    for (int k0 = 0; k0 < 1536; k0 += 64) {
        int abyte = (k0 < 1024 ? k0 : k0 - 1024) * 2;
        int bbyte = (k0 < 512 ? k0 : k0 - 512) * 2;
        #pragma unroll
        for (int inst = 0; inst < 2; ++inst) {
            int row = wave * 16 + inst * 8 + r8;
            short8 av = *reinterpret_cast<const short8*>(
                Ab + (size_t)(m0 + row) * 2048 + abyte + c8 * 16);
            *reinterpret_cast<short8*>(AlB + row * 128 + ((c8 ^ r8) * 16)) = av;
            short8 bv = *reinterpret_cast<const short8*>(
                Bb + (size_t)(n0 + row) * 2048 + bbyte + c8 * 16);
            *reinterpret_cast<short8*>(BlB + row * 128 + ((c8 ^ r8) * 16)) = bv;
        }
        __syncthreads();
        #pragma unroll
        for (int kk = 0; kk < 2; ++kk) {
            short8 af[2], bf[2];
            #pragma unroll
            for (int i = 0; i < 2; ++i) {
                int ra = wr * 32 + i * 16 + l15;
                int sa = (kk * 4 + kb) ^ (ra & 7);
                af[i] = *reinterpret_cast<const short8*>(AlB + ra * 128 + sa * 16);
                int rb = wc * 32 + i * 16 + l15;
                int sbx = (kk * 4 + kb) ^ (rb & 7);
                bf[i] = *reinterpret_cast<const short8*>(BlB + rb * 128 + sbx * 16);
            }
            #pragma unroll
            for (int i = 0; i < 2; ++i)
                #pragma unroll
                for (int j = 0; j < 2; ++j)
                    acc[i][j] = __builtin_amdgcn_mfma_f32_16x16x32_bf16(
                        af[i], bf[j], acc[i][j], 0, 0, 0);
        }
        __syncthreads();
    }

    const int b = m0 >> 8;
    if (by < 8) {
        // sh: a = n, t = m&255, scaled by PS
        #pragma unroll
        for (int i = 0; i < 2; ++i) {
            int t0 = (m0 & 255) + wr * 32 + i * 16 + kb * 4;
            #pragma unroll
            for (int j = 0; j < 2; ++j) {
                int n = n0 + wc * 32 + j * 16 + l15;
                float bbv = bsh[n];
                float4 v;
                v.x = (acc[i][j][0] + bbv) * PS;
                v.y = (acc[i][j][1] + bbv) * PS;
                v.z = (acc[i][j][2] + bbv) * PS;
                v.w = (acc[i][j][3] + bbv) * PS;
                *reinterpret_cast<float4*>(&shT[((size_t)b * 512 + n) * 256 + t0]) = v;
            }
        }
    } else if (by < 16) {
        #pragma unroll
        for (int i = 0; i < 2; ++i) {
            #pragma unroll
            for (int j = 0; j < 2; ++j) {
                int n = n0 - 512 + wc * 32 + j * 16 + l15;
                float bbv = bsi[n];
                #pragma unroll
                for (int r = 0; r < 4; ++r) {
                    int m = m0 + wr * 32 + i * 16 + kb * 4 + r;
                    si2[(size_t)m * 512 + n] = (acc[i][j][r] + bbv) * PS;
                }
            }
        }
    } else {
        int slot = (by - 16) * 2 + wc;
        #pragma unroll
        for (int i = 0; i < 2; ++i) {
            float p0 = 0.f, p1 = 0.f, p2 = 0.f, p3 = 0.f;
            #pragma unroll
            for (int j = 0; j < 2; ++j) {
                int n = n0 - 1024 + wc * 32 + j * 16 + l15;
                float add = bih[n] + ii[b * 512 + n];
                float w = iv[n];
                p0 = fmaf(w, fast_tanh(acc[i][j][0] + add), p0);
                p1 = fmaf(w, fast_tanh(acc[i][j][1] + add), p1);
                p2 = fmaf(w, fast_tanh(acc[i][j][2] + add), p2);
                p3 = fmaf(w, fast_tanh(acc[i][j][3] + add), p3);
            }
            #pragma unroll
            for (int off = 1; off < 16; off <<= 1) {
                p0 += __shfl_xor(p0, off);
                p1 += __shfl_xor(p1, off);
                p2 += __shfl_xor(p2, off);
                p3 += __shfl_xor(p3, off);
            }
            int mb = m0 + wr * 32 + i * 16 + kb * 4;
            if (l15 == 0) ipart[slot * 2048 + mb + 0] = p0;
            if (l15 == 1) ipart[slot * 2048 + mb + 1] = p1;
            if (l15 == 2) ipart[slot * 2048 + mb + 2] = p2;
            if (l15 == 3) ipart[slot * 2048 + mb + 3] = p3;
        }
    }
}

// ---------------- old fp32 fallback GEMM (round-1, outputs prescaled) ----------------
#define TS 64
#define KS 16
#define LPAD 72

__global__ __launch_bounds__(256) void k1_gemm_old(
    const float* __restrict__ SO,
    const float* __restrict__ Wsh, const float* __restrict__ bsh,
    const float* __restrict__ Wsi, const float* __restrict__ bsi,
    const float* __restrict__ Wih, const float* __restrict__ bih,
    const float* __restrict__ ii, const float* __restrict__ iv,
    float* __restrict__ shT, float* __restrict__ si_o, float* __restrict__ ipart) {
    const int mode = blockIdx.z;
    const float* W;
    const float* bias;
    if (mode == 0)      { W = Wsh; bias = bsh; }
    else if (mode == 1) { W = Wsi; bias = bsi; }
    else                { W = Wih; bias = bih; }

    const int m0 = blockIdx.x * TS;
    const int n0 = blockIdx.y * TS;
    const int tid = threadIdx.x;
    const int tx = tid & 15, ty = tid >> 4;

    __shared__ __align__(16) float As[KS][LPAD];
    __shared__ __align__(16) float Bs[KS][LPAD];
    __shared__ __align__(16) float Cs[TS][LPAD];

    float acc[4][4] = {};
    const int arow = tid >> 2;
    const int akc  = (tid & 3) * 4;
    const int brw  = tid >> 4;
    const int bnc  = (tid & 15) * 4;

    for (int k0 = 0; k0 < DD; k0 += KS) {
        float4 av = *reinterpret_cast<const float4*>(&SO[(m0 + arow) * DD + k0 + akc]);
        As[akc + 0][arow] = av.x;
        As[akc + 1][arow] = av.y;
        As[akc + 2][arow] = av.z;
        As[akc + 3][arow] = av.w;
        float4 bv = *reinterpret_cast<const float4*>(&W[(k0 + brw) * AA + n0 + bnc]);
        *reinterpret_cast<float4*>(&Bs[brw][bnc]) = bv;
        __syncthreads();
        #pragma unroll
        for (int kk = 0; kk < KS; ++kk) {
            float4 a4 = *reinterpret_cast<const float4*>(&As[kk][ty * 4]);
            float4 b4 = *reinterpret_cast<const float4*>(&Bs[kk][tx * 4]);
            float av_[4] = {a4.x, a4.y, a4.z, a4.w};
            float bv_[4] = {b4.x, b4.y, b4.z, b4.w};
            #pragma unroll
            for (int i = 0; i < 4; ++i)
                #pragma unroll
                for (int j = 0; j < 4; ++j)
                    acc[i][j] = fmaf(av_[i], bv_[j], acc[i][j]);
        }
        __syncthreads();
    }

    if (mode == 1) {
        #pragma unroll
        for (int i = 0; i < 4; ++i) {
            int m = m0 + ty * 4 + i;
            float4 v;
            v.x = (acc[i][0] + bias[n0 + tx * 4 + 0]) * PS;
            v.y = (acc[i][1] + bias[n0 + tx * 4 + 1]) * PS;
            v.z = (acc[i][2] + bias[n0 + tx * 4 + 2]) * PS;
            v.w = (acc[i][3] + bias[n0 + tx * 4 + 3]) * PS;
            *reinterpret_cast<float4*>(&si_o[m * AA + n0 + tx * 4]) = v;
        }
    } else if (mode == 0) {
        #pragma unroll
        for (int i = 0; i < 4; ++i)
            #pragma unroll
            for (int j = 0; j < 4; ++j)
                Cs[tx * 4 + j][ty * 4 + i] = (acc[i][j] + bias[n0 + tx * 4 + j]) * PS;
        __syncthreads();
        int row = tid >> 2, part = tid & 3;
        int bb = m0 >> 8;
        int tstart = (m0 & 255) + part * 16;
        float* dst = &shT[bb * (AA * TT) + (n0 + row) * TT + tstart];
        #pragma unroll
        for (int q = 0; q < 4; ++q) {
            float4 v = *reinterpret_cast<const float4*>(&Cs[row][part * 16 + q * 4]);
            *reinterpret_cast<float4*>(&dst[q * 4]) = v;
        }
    } else {
        int bb = m0 >> 8;
        #pragma unroll
        for (int i = 0; i < 4; ++i) {
            float p = 0.f;
            #pragma unroll
            for (int j = 0; j < 4; ++j) {
                int n = n0 + tx * 4 + j;
                float x = acc[i][j] + bias[n] + ii[bb * AA + n];
                p = fmaf(iv[n], fast_tanh(x), p);
            }
            Cs[ty * 4 + i][tx] = p;
        }
        __syncthreads();
        if (tid < 64) {
            float s = 0.f;
            #pragma unroll
            for (int k = 0; k < 16; ++k) s += Cs[tid][k];
            ipart[blockIdx.y * (BB * TT) + m0 + tid] = s;
        }
    }
}

// ---------------- k2: intent softmax + c_intent ----------------
__global__ __launch_bounds__(256) void k2_intent(const float* __restrict__ SO,
                                                 const float* __restrict__ ipart,
                                                 float* __restrict__ out_cint,
                                                 int npart) {
    int b = blockIdx.x, tid = threadIdx.x;
    __shared__ float red[256];
    __shared__ float wl[256];
    float s = 0.f;
    for (int nb = 0; nb < npart; ++nb) s += ipart[nb * (BB * TT) + b * TT + tid];
    red[tid] = s;
    __syncthreads();
    for (int off = 128; off > 0; off >>= 1) {
        if (tid < off) red[tid] = fmaxf(red[tid], red[tid + off]);
        __syncthreads();
    }
    float m = red[0];
    __syncthreads();
    float e = __builtin_amdgcn_exp2f((s - m) * LOG2E);
    red[tid] = e;
    __syncthreads();
    for (int off = 128; off > 0; off >>= 1) {
        if (tid < off) red[tid] += red[tid + off];
        __syncthreads();
    }
    float w = e * __builtin_amdgcn_rcpf(red[0]);
    wl[tid] = w;
    __syncthreads();
    #pragma unroll
    for (int half = 0; half < 2; ++half) {
        int d = tid + half * 256;
        float acc = 0.f;
        #pragma unroll 4
        for (int s2 = 0; s2 < TT; ++s2)
            acc = fmaf(wl[s2], SO[(b * TT + s2) * DD + d], acc);
        out_cint[b * DD + d] = acc;
    }
}

// ---------------- k3: fused slot score + softmax + PV (TGROUP=2) ----------------
// shT and si2 are prescaled by PS. weight ∝ exp2(PS*(ymin - y)), y = sum v*rcp(1+exp2(h2+s2))
__global__ __launch_bounds__(256) void k3_slot2(const float* __restrict__ SO,
                                                const float* __restrict__ shT,
                                                const float* __restrict__ si2,
                                                const float* __restrict__ sv_g,
                                                float* __restrict__ out_cslot) {
    const int bid = blockIdx.x;
    const int b = bid & 7;
    const int t0 = (bid >> 3) * 2;
    const int tid = threadIdx.x;
    const int lane = tid & 63, wave = tid >> 6;

    __shared__ float sil0[AA], sil1[AA], sv[AA];
    __shared__ float wl[2][TT];
    __shared__ float redm[2][8];

    sv[tid]       = sv_g[tid];
    sv[tid + 256] = sv_g[tid + 256];
    sil0[tid]       = si2[(size_t)(b * TT + t0) * AA + tid];
    sil0[tid + 256] = si2[(size_t)(b * TT + t0) * AA + tid + 256];
    sil1[tid]       = si2[(size_t)(b * TT + t0 + 1) * AA + tid];
    sil1[tid + 256] = si2[(size_t)(b * TT + t0 + 1) * AA + tid + 256];
    __syncthreads();

    const float* sb = &shT[(size_t)b * AA * TT];
    float y0 = 0.f, y1 = 0.f;
    #pragma unroll 8
    for (int a = 0; a < AA; ++a) {
        float h = sb[a * TT + tid];
        float v = sv[a];
        float e0 = __builtin_amdgcn_exp2f(h + sil0[a]);
        y0 = fmaf(v, __builtin_amdgcn_rcpf(1.0f + e0), y0);
        float e1 = __builtin_amdgcn_exp2f(h + sil1[a]);
        y1 = fmaf(v, __builtin_amdgcn_rcpf(1.0f + e1), y1);
    }

    float ys[2] = {y0, y1};
    #pragma unroll
    for (int q = 0; q < 2; ++q) {
        float y = ys[q];
        float mn = y;
        #pragma unroll
        for (int off = 1; off < 64; off <<= 1)
            mn = fminf(mn, __shfl_xor(mn, off));
        if (lane == 0) redm[q][wave] = mn;
        __syncthreads();
        mn = fminf(fminf(redm[q][0], redm[q][1]), fminf(redm[q][2], redm[q][3]));
        float e = __builtin_amdgcn_exp2f(PS * (mn - y));
        float sm = e;
        #pragma unroll
        for (int off = 1; off < 64; off <<= 1)
            sm += __shfl_xor(sm, off);
        if (lane == 0) redm[q][4 + wave] = sm;
        __syncthreads();
        sm = (redm[q][4] + redm[q][5]) + (redm[q][6] + redm[q][7]);
        wl[q][tid] = e * __builtin_amdgcn_rcpf(sm);
    }
    __syncthreads();

    #pragma unroll
    for (int half = 0; half < 2; ++half) {
        int d = tid + half * 256;
        float c0 = 0.f, c1 = 0.f;
        #pragma unroll 4
        for (int s2 = 0; s2 < TT; ++s2) {
            float so = SO[((size_t)b * TT + s2) * DD + d];
            c0 = fmaf(wl[0][s2], so, c0);
            c1 = fmaf(wl[1][s2], so, c1);
        }
        out_cslot[((size_t)b * TT + t0 + 0) * DD + d] = c0;
        out_cslot[((size_t)b * TT + t0 + 1) * DD + d] = c1;
    }
}

extern "C" void kernel_launch(void* const* d_in, const int* in_sizes, int n_in,
                              void* d_out, int out_size, void* d_ws, size_t ws_size,
                              hipStream_t stream) {
    const float* SO  = (const float*)d_in[0];
    const float* FS  = (const float*)d_in[1];
    const float* IV  = (const float*)d_in[2];
    const float* Wih = (const float*)d_in[3];
    const float* bih = (const float*)d_in[4];
    const float* Wii = (const float*)d_in[5];
    const float* bii = (const float*)d_in[6];
    const float* SV  = (const float*)d_in[7];
    const float* Wsh = (const float*)d_in[8];
    const float* bsh = (const float*)d_in[9];
    const float* Wsi = (const float*)d_in[10];
    const float* bsi = (const float*)d_in[11];

    float* ws    = (float*)d_ws;
    float* shT   = ws;                 // [8][512][256]        1,048,576 f (prescaled)
    float* si2   = ws + 1048576;       // [2048][512]          1,048,576 f (prescaled)
    float* ii    = ws + 2097152;       // [8][512]             4,096 f
    float* ipart = ws + 2101248;       // [16][2048]           32,768 f
    ushort* Ast  = (ushort*)(ws + 2134016);  // [2048][1024] bf16
    ushort* Wt   = (ushort*)(ws + 3182592);  // [1536][1024] bf16
    const size_t NEED = (size_t)3969024 * 4;

    float* out_cslot = (float*)d_out;
    float* out_cint  = out_cslot + BB * TT * DD;

    if (ws_size >= NEED) {
        conv_A<<<1024, 256, 0, stream>>>(SO, Ast);
        conv_W<<<dim3(16, 16, 3), 256, 0, stream>>>(Wsh, Wsi, Wih, Wt);
        k0_ii<<<dim3(BB, 2), 256, 0, stream>>>(FS, Wii, bii, ii);
        gemm_mfma<<<dim3(32, 24), 256, 0, stream>>>(Ast, Wt, bsh, bsi, bih, ii, IV,
                                                    shT, si2, ipart);
        k2_intent<<<BB, 256, 0, stream>>>(SO, ipart, out_cint, 16);
        k3_slot2<<<1024, 256, 0, stream>>>(SO, shT, si2, SV, out_cslot);
    } else {
        k0_ii<<<dim3(BB, 2), 256, 0, stream>>>(FS, Wii, bii, ii);
        k1_gemm_old<<<dim3(32, 8, 3), 256, 0, stream>>>(SO, Wsh, bsh, Wsi, bsi, Wih, bih,
                                                        ii, IV, shT, si2, ipart);
        k2_intent<<<BB, 256, 0, stream>>>(SO, ipart, out_cint, 8);
        k3_slot2<<<1024, 256, 0, stream>>>(SO, shT, si2, SV, out_cslot);
    }
}

// Round 3
// 107.438 us; speedup vs baseline: 2.3729x; 1.8054x over previous
//
#include <hip/hip_runtime.h>

#define BB 8
#define TT 256
#define DD 512
#define AA 512

#define PS 2.8853900817779268f   // 2*log2(e)
#define LOG2E 1.4426950408889634f

typedef __attribute__((ext_vector_type(8))) short short8;
typedef __attribute__((ext_vector_type(4))) float f32x4;

__device__ __forceinline__ float fast_tanh(float x) {
    float e = __builtin_amdgcn_exp2f(x * PS);
    float r = __builtin_amdgcn_rcpf(1.0f + e);
    return fmaf(-2.0f, r, 1.0f);
}

__device__ __forceinline__ ushort f2bf(float x) {
    uint u = __float_as_uint(x);
    uint r = (u + 0x7fffu + ((u >> 16) & 1u)) >> 16;  // RNE
    return (ushort)r;
}
__device__ __forceinline__ float bf2f(ushort h) {
    return __uint_as_float(((uint)h) << 16);
}

// ---------------- prep: conv_A (blocks 0..1023) + conv_W (1024..1791) + k0 (1792..1807) --
__global__ __launch_bounds__(256) void prep(const float* __restrict__ SO,
                                            ushort* __restrict__ Ast,
                                            const float* __restrict__ Wsh,
                                            const float* __restrict__ Wsi,
                                            const float* __restrict__ Wih,
                                            ushort* __restrict__ Wt,
                                            const float* __restrict__ fs_g,
                                            const float* __restrict__ Wii,
                                            const float* __restrict__ bii,
                                            float* __restrict__ ii) {
    const int bid = blockIdx.x;
    const int tid = threadIdx.x;
    __shared__ float T[32][33];
    __shared__ float fs[DD];

    if (bid < 1024) {
        // conv_A: SO[2048][512] f32 -> Ast bf16 [2048][1024] = [hi|lo]
        int qid = bid * 256 + tid;
        int m = qid >> 7;
        int k4 = (qid & 127) * 4;
        float4 v = *reinterpret_cast<const float4*>(&SO[(size_t)m * 512 + k4]);
        ushort4 hi, lo;
        hi.x = f2bf(v.x); lo.x = f2bf(v.x - bf2f(hi.x));
        hi.y = f2bf(v.y); lo.y = f2bf(v.y - bf2f(hi.y));
        hi.z = f2bf(v.z); lo.z = f2bf(v.z - bf2f(hi.z));
        hi.w = f2bf(v.w); lo.w = f2bf(v.w - bf2f(hi.w));
        *reinterpret_cast<ushort4*>(&Ast[(size_t)m * 1024 + k4])       = hi;
        *reinterpret_cast<ushort4*>(&Ast[(size_t)m * 1024 + 512 + k4]) = lo;
    } else if (bid < 1792) {
        // conv_W: transpose-convert 3x W[512][512] -> Wt bf16 [1536][1024]
        int lbid = bid - 1024;
        int z = lbid >> 8;
        int rem = lbid & 255;
        const float* W = (z == 0) ? Wsh : (z == 1) ? Wsi : Wih;
        int k0 = (rem & 15) * 32, n0 = (rem >> 4) * 32;
        int tx = tid & 31, ty = tid >> 5;
        #pragma unroll
        for (int r = 0; r < 4; ++r) {
            int kl = ty * 4 + r;
            T[kl][tx] = W[(size_t)(k0 + kl) * 512 + n0 + tx];
        }
        __syncthreads();
        size_t nbase = (size_t)z * 512 + n0;
        #pragma unroll
        for (int r = 0; r < 4; ++r) {
            int nl = ty * 4 + r;
            float v = T[tx][nl];
            ushort hi = f2bf(v);
            ushort lo = f2bf(v - bf2f(hi));
            Wt[(nbase + nl) * 1024 + k0 + tx]       = hi;
            Wt[(nbase + nl) * 1024 + 512 + k0 + tx] = lo;
        }
    } else {
        // k0: ii = final_state @ W_ii + b_ii
        int lbid = bid - 1792;
        int b = lbid >> 1, half = lbid & 1;
        int a = half * 256 + tid;
        fs[tid]       = fs_g[b * DD + tid];
        fs[tid + 256] = fs_g[b * DD + tid + 256];
        __syncthreads();
        float acc = bii[a];
        #pragma unroll 8
        for (int d = 0; d < DD; ++d)
            acc = fmaf(fs[d], Wii[(size_t)d * AA + a], acc);
        ii[b * AA + a] = acc;
    }
}

// ---------------- gemm_mfma: C[2048][1536] = Ast' x Wt', fused epilogues ----------------
// N regions: [0,512)=sh -> EhT[b][a][t] = exp2(PS*(sh+bsh)) ; [512,1024)=si -> Es[m][n]=exp2(PS*(si+bsi));
//            [1024,1536)=ih -> ipart[slot][m] = partial sum iv*tanh(ih+ii+bih)
__global__ __launch_bounds__(256) void gemm_mfma(
    const ushort* __restrict__ Ast, const ushort* __restrict__ Wt,
    const float* __restrict__ bsh, const float* __restrict__ bsi,
    const float* __restrict__ bih,
    const float* __restrict__ ii, const float* __restrict__ iv,
    float* __restrict__ EhT, float* __restrict__ Es, float* __restrict__ ipart) {
    __shared__ ushort Al[64 * 64];
    __shared__ ushort Bl[64 * 64];
    const int tid = threadIdx.x;
    const int wave = tid >> 6, lane = tid & 63;
    const int wr = wave >> 1, wc = wave & 1;
    const int m0 = blockIdx.x * 64;
    const int by = blockIdx.y;
    const int n0 = by * 64;
    const int r8 = lane >> 3, c8 = lane & 7;
    const int l15 = lane & 15, kb = lane >> 4;

    f32x4 acc[2][2] = {};

    const char* Ab = reinterpret_cast<const char*>(Ast);
    const char* Bb = reinterpret_cast<const char*>(Wt);
    char* AlB = reinterpret_cast<char*>(Al);
    char* BlB = reinterpret_cast<char*>(Bl);

    for (int k0 = 0; k0 < 1536; k0 += 64) {
        int abyte = (k0 < 1024 ? k0 : k0 - 1024) * 2;
        int bbyte = (k0 < 512 ? k0 : k0 - 512) * 2;
        #pragma unroll
        for (int inst = 0; inst < 2; ++inst) {
            int row = wave * 16 + inst * 8 + r8;
            short8 av = *reinterpret_cast<const short8*>(
                Ab + (size_t)(m0 + row) * 2048 + abyte + c8 * 16);
            *reinterpret_cast<short8*>(AlB + row * 128 + ((c8 ^ r8) * 16)) = av;
            short8 bv = *reinterpret_cast<const short8*>(
                Bb + (size_t)(n0 + row) * 2048 + bbyte + c8 * 16);
            *reinterpret_cast<short8*>(BlB + row * 128 + ((c8 ^ r8) * 16)) = bv;
        }
        __syncthreads();
        #pragma unroll
        for (int kk = 0; kk < 2; ++kk) {
            short8 af[2], bf[2];
            #pragma unroll
            for (int i = 0; i < 2; ++i) {
                int ra = wr * 32 + i * 16 + l15;
                int sa = (kk * 4 + kb) ^ (ra & 7);
                af[i] = *reinterpret_cast<const short8*>(AlB + ra * 128 + sa * 16);
                int rb = wc * 32 + i * 16 + l15;
                int sbx = (kk * 4 + kb) ^ (rb & 7);
                bf[i] = *reinterpret_cast<const short8*>(BlB + rb * 128 + sbx * 16);
            }
            #pragma unroll
            for (int i = 0; i < 2; ++i)
                #pragma unroll
                for (int j = 0; j < 2; ++j)
                    acc[i][j] = __builtin_amdgcn_mfma_f32_16x16x32_bf16(
                        af[i], bf[j], acc[i][j], 0, 0, 0);
        }
        __syncthreads();
    }

    const int b = m0 >> 8;
    if (by < 8) {
        #pragma unroll
        for (int i = 0; i < 2; ++i) {
            int t0 = (m0 & 255) + wr * 32 + i * 16 + kb * 4;
            #pragma unroll
            for (int j = 0; j < 2; ++j) {
                int n = n0 + wc * 32 + j * 16 + l15;
                float bbv = bsh[n];
                float4 v;
                v.x = __builtin_amdgcn_exp2f((acc[i][j][0] + bbv) * PS);
                v.y = __builtin_amdgcn_exp2f((acc[i][j][1] + bbv) * PS);
                v.z = __builtin_amdgcn_exp2f((acc[i][j][2] + bbv) * PS);
                v.w = __builtin_amdgcn_exp2f((acc[i][j][3] + bbv) * PS);
                *reinterpret_cast<float4*>(&EhT[((size_t)b * 512 + n) * 256 + t0]) = v;
            }
        }
    } else if (by < 16) {
        #pragma unroll
        for (int i = 0; i < 2; ++i) {
            #pragma unroll
            for (int j = 0; j < 2; ++j) {
                int n = n0 - 512 + wc * 32 + j * 16 + l15;
                float bbv = bsi[n];
                #pragma unroll
                for (int r = 0; r < 4; ++r) {
                    int m = m0 + wr * 32 + i * 16 + kb * 4 + r;
                    Es[(size_t)m * 512 + n] = __builtin_amdgcn_exp2f((acc[i][j][r] + bbv) * PS);
                }
            }
        }
    } else {
        int slot = (by - 16) * 2 + wc;
        #pragma unroll
        for (int i = 0; i < 2; ++i) {
            float p0 = 0.f, p1 = 0.f, p2 = 0.f, p3 = 0.f;
            #pragma unroll
            for (int j = 0; j < 2; ++j) {
                int n = n0 - 1024 + wc * 32 + j * 16 + l15;
                float add = bih[n] + ii[b * 512 + n];
                float w = iv[n];
                p0 = fmaf(w, fast_tanh(acc[i][j][0] + add), p0);
                p1 = fmaf(w, fast_tanh(acc[i][j][1] + add), p1);
                p2 = fmaf(w, fast_tanh(acc[i][j][2] + add), p2);
                p3 = fmaf(w, fast_tanh(acc[i][j][3] + add), p3);
            }
            #pragma unroll
            for (int off = 1; off < 16; off <<= 1) {
                p0 += __shfl_xor(p0, off);
                p1 += __shfl_xor(p1, off);
                p2 += __shfl_xor(p2, off);
                p3 += __shfl_xor(p3, off);
            }
            int mb = m0 + wr * 32 + i * 16 + kb * 4;
            if (l15 == 0) ipart[slot * 2048 + mb + 0] = p0;
            if (l15 == 1) ipart[slot * 2048 + mb + 1] = p1;
            if (l15 == 2) ipart[slot * 2048 + mb + 2] = p2;
            if (l15 == 3) ipart[slot * 2048 + mb + 3] = p3;
        }
    }
}

// ---------------- fallback fp32 GEMM (writes exp2'd EhT/Es) ----------------
#define TS 64
#define KS 16
#define LPAD 72

__global__ __launch_bounds__(256) void k0_ii(const float* __restrict__ fs_g,
                                             const float* __restrict__ Wii,
                                             const float* __restrict__ bii,
                                             float* __restrict__ ii) {
    int b = blockIdx.x, tid = threadIdx.x;
    int a = blockIdx.y * 256 + tid;
    __shared__ float fs[DD];
    fs[tid]       = fs_g[b * DD + tid];
    fs[tid + 256] = fs_g[b * DD + tid + 256];
    __syncthreads();
    float acc = bii[a];
    #pragma unroll 8
    for (int d = 0; d < DD; ++d)
        acc = fmaf(fs[d], Wii[(size_t)d * AA + a], acc);
    ii[b * AA + a] = acc;
}

__global__ __launch_bounds__(256) void k1_gemm_old(
    const float* __restrict__ SO,
    const float* __restrict__ Wsh, const float* __restrict__ bsh,
    const float* __restrict__ Wsi, const float* __restrict__ bsi,
    const float* __restrict__ Wih, const float* __restrict__ bih,
    const float* __restrict__ ii, const float* __restrict__ iv,
    float* __restrict__ EhT, float* __restrict__ Es, float* __restrict__ ipart) {
    const int mode = blockIdx.z;
    const float* W;
    const float* bias;
    if (mode == 0)      { W = Wsh; bias = bsh; }
    else if (mode == 1) { W = Wsi; bias = bsi; }
    else                { W = Wih; bias = bih; }

    const int m0 = blockIdx.x * TS;
    const int n0 = blockIdx.y * TS;
    const int tid = threadIdx.x;
    const int tx = tid & 15, ty = tid >> 4;

    __shared__ __align__(16) float As[KS][LPAD];
    __shared__ __align__(16) float Bs[KS][LPAD];
    __shared__ __align__(16) float Cs[TS][LPAD];

    float acc[4][4] = {};
    const int arow = tid >> 2;
    const int akc  = (tid & 3) * 4;
    const int brw  = tid >> 4;
    const int bnc  = (tid & 15) * 4;

    for (int k0 = 0; k0 < DD; k0 += KS) {
        float4 av = *reinterpret_cast<const float4*>(&SO[(m0 + arow) * DD + k0 + akc]);
        As[akc + 0][arow] = av.x;
        As[akc + 1][arow] = av.y;
        As[akc + 2][arow] = av.z;
        As[akc + 3][arow] = av.w;
        float4 bv = *reinterpret_cast<const float4*>(&W[(k0 + brw) * AA + n0 + bnc]);
        *reinterpret_cast<float4*>(&Bs[brw][bnc]) = bv;
        __syncthreads();
        #pragma unroll
        for (int kk = 0; kk < KS; ++kk) {
            float4 a4 = *reinterpret_cast<const float4*>(&As[kk][ty * 4]);
            float4 b4 = *reinterpret_cast<const float4*>(&Bs[kk][tx * 4]);
            float av_[4] = {a4.x, a4.y, a4.z, a4.w};
            float bv_[4] = {b4.x, b4.y, b4.z, b4.w};
            #pragma unroll
            for (int i = 0; i < 4; ++i)
                #pragma unroll
                for (int j = 0; j < 4; ++j)
                    acc[i][j] = fmaf(av_[i], bv_[j], acc[i][j]);
        }
        __syncthreads();
    }

    if (mode == 1) {
        #pragma unroll
        for (int i = 0; i < 4; ++i) {
            int m = m0 + ty * 4 + i;
            float4 v;
            v.x = __builtin_amdgcn_exp2f((acc[i][0] + bias[n0 + tx * 4 + 0]) * PS);
            v.y = __builtin_amdgcn_exp2f((acc[i][1] + bias[n0 + tx * 4 + 1]) * PS);
            v.z = __builtin_amdgcn_exp2f((acc[i][2] + bias[n0 + tx * 4 + 2]) * PS);
            v.w = __builtin_amdgcn_exp2f((acc[i][3] + bias[n0 + tx * 4 + 3]) * PS);
            *reinterpret_cast<float4*>(&Es[(size_t)m * AA + n0 + tx * 4]) = v;
        }
    } else if (mode == 0) {
        #pragma unroll
        for (int i = 0; i < 4; ++i)
            #pragma unroll
            for (int j = 0; j < 4; ++j)
                Cs[tx * 4 + j][ty * 4 + i] =
                    __builtin_amdgcn_exp2f((acc[i][j] + bias[n0 + tx * 4 + j]) * PS);
        __syncthreads();
        int row = tid >> 2, part = tid & 3;
        int bb = m0 >> 8;
        int tstart = (m0 & 255) + part * 16;
        float* dst = &EhT[bb * (AA * TT) + (n0 + row) * TT + tstart];
        #pragma unroll
        for (int q = 0; q < 4; ++q) {
            float4 v = *reinterpret_cast<const float4*>(&Cs[row][part * 16 + q * 4]);
            *reinterpret_cast<float4*>(&dst[q * 4]) = v;
        }
    } else {
        int bb = m0 >> 8;
        #pragma unroll
        for (int i = 0; i < 4; ++i) {
            float p = 0.f;
            #pragma unroll
            for (int j = 0; j < 4; ++j) {
                int n = n0 + tx * 4 + j;
                float x = acc[i][j] + bias[n] + ii[bb * AA + n];
                p = fmaf(iv[n], fast_tanh(x), p);
            }
            Cs[ty * 4 + i][tx] = p;
        }
        __syncthreads();
        if (tid < 64) {
            float s = 0.f;
            #pragma unroll
            for (int k = 0; k < 16; ++k) s += Cs[tid][k];
            ipart[blockIdx.y * 2048 + m0 + tid] = s;
        }
    }
}

// ---------------- k3_fused: slot score/softmax/PV (blocks 0..511) + intent (512..519) ----
// sigma = rcp(1 + Eh*Es); weight over s ∝ exp2(PS*(ymin - y)), y = sum_a v*sigma
__global__ __launch_bounds__(512) void k3_fused(const float* __restrict__ SO,
                                                const float* __restrict__ EhT,
                                                const float* __restrict__ Es,
                                                const float* __restrict__ sv_g,
                                                const float* __restrict__ ipart,
                                                float* __restrict__ out_cslot,
                                                float* __restrict__ out_cint,
                                                int npart) {
    const int bid = blockIdx.x;
    const int tid = threadIdx.x;

    __shared__ __align__(16) float est[512][4];
    __shared__ float sv[512];
    __shared__ float yp[2][4][256];
    __shared__ __align__(16) float wlt[256][4];
    __shared__ float redm[4][4];
    __shared__ float reds[4][4];
    __shared__ float redI[256];
    __shared__ float wlI[256];

    if (bid < 512) {
        const int b = bid & 7;          // XCD-affine
        const int t0 = (bid >> 3) * 4;
        const int s = tid & 255, ah = tid >> 8;

        // stage Es rows (4 t's, transposed) + sv
        {
            const float* esrc = &Es[(size_t)(b * 256 + t0) * 512];
            #pragma unroll
            for (int i = tid; i < 2048; i += 512) est[i & 511][i >> 9] = esrc[i];
            sv[tid] = sv_g[tid];
        }
        __syncthreads();

        const int abase = ah * 256;
        const float* hp = &EhT[((size_t)b * 512 + abase) * 256 + s];
        float y0 = 0.f, y1 = 0.f, y2 = 0.f, y3 = 0.f;
        for (int a0 = 0; a0 < 256; a0 += 8) {
            float h[8];
            #pragma unroll
            for (int u = 0; u < 8; ++u) h[u] = hp[(a0 + u) * 256];
            #pragma unroll
            for (int u = 0; u < 8; ++u) {
                int a = abase + a0 + u;
                float4 e4 = *reinterpret_cast<const float4*>(&est[a][0]);
                float v = sv[a];
                float x0 = fmaf(h[u], e4.x, 1.0f);
                y0 = fmaf(v, __builtin_amdgcn_rcpf(x0), y0);
                float x1 = fmaf(h[u], e4.y, 1.0f);
                y1 = fmaf(v, __builtin_amdgcn_rcpf(x1), y1);
                float x2 = fmaf(h[u], e4.z, 1.0f);
                y2 = fmaf(v, __builtin_amdgcn_rcpf(x2), y2);
                float x3 = fmaf(h[u], e4.w, 1.0f);
                y3 = fmaf(v, __builtin_amdgcn_rcpf(x3), y3);
            }
        }
        yp[ah][0][s] = y0; yp[ah][1][s] = y1; yp[ah][2][s] = y2; yp[ah][3][s] = y3;
        __syncthreads();

        const int wg = (tid >> 6) & 3;
        #pragma unroll
        for (int r = 0; r < 2; ++r) {
            int q = ah * 2 + r;
            float y = yp[0][q][s] + yp[1][q][s];
            float mn = y;
            #pragma unroll
            for (int off = 1; off < 64; off <<= 1)
                mn = fminf(mn, __shfl_xor(mn, off));
            if ((tid & 63) == 0) redm[q][wg] = mn;
            __syncthreads();
            mn = fminf(fminf(redm[q][0], redm[q][1]), fminf(redm[q][2], redm[q][3]));
            float e = __builtin_amdgcn_exp2f(PS * (mn - y));
            float sm = e;
            #pragma unroll
            for (int off = 1; off < 64; off <<= 1)
                sm += __shfl_xor(sm, off);
            if ((tid & 63) == 0) reds[q][wg] = sm;
            __syncthreads();
            sm = (reds[q][0] + reds[q][1]) + (reds[q][2] + reds[q][3]);
            wlt[s][q] = e * __builtin_amdgcn_rcpf(sm);
        }
        __syncthreads();

        // PV: thread owns d = tid
        const int d = tid;
        const float* sop = &SO[(size_t)b * 256 * 512 + d];
        float c0 = 0.f, c1 = 0.f, c2 = 0.f, c3 = 0.f;
        for (int s0 = 0; s0 < 256; s0 += 4) {
            float so[4];
            #pragma unroll
            for (int u = 0; u < 4; ++u) so[u] = sop[(s0 + u) * 512];
            #pragma unroll
            for (int u = 0; u < 4; ++u) {
                float4 w4 = *reinterpret_cast<const float4*>(&wlt[s0 + u][0]);
                c0 = fmaf(w4.x, so[u], c0);
                c1 = fmaf(w4.y, so[u], c1);
                c2 = fmaf(w4.z, so[u], c2);
                c3 = fmaf(w4.w, so[u], c3);
            }
        }
        float* op = &out_cslot[((size_t)(b * 256 + t0)) * 512 + d];
        op[0] = c0; op[512] = c1; op[1024] = c2; op[1536] = c3;
    } else {
        // ---- intent path ----
        const int b = bid - 512;
        float sc = 0.f;
        if (tid < 256) {
            for (int nb = 0; nb < npart; ++nb) sc += ipart[nb * 2048 + b * 256 + tid];
            redI[tid] = sc;
        }
        __syncthreads();
        for (int off = 128; off > 0; off >>= 1) {
            if (tid < off) redI[tid] = fmaxf(redI[tid], redI[tid + off]);
            __syncthreads();
        }
        float mx = redI[0];
        __syncthreads();
        float e = 0.f;
        if (tid < 256) { e = __builtin_amdgcn_exp2f((sc - mx) * LOG2E); redI[tid] = e; }
        __syncthreads();
        for (int off = 128; off > 0; off >>= 1) {
            if (tid < off) redI[tid] += redI[tid + off];
            __syncthreads();
        }
        if (tid < 256) wlI[tid] = e * __builtin_amdgcn_rcpf(redI[0]);
        __syncthreads();
        const int d = tid;
        float c = 0.f;
        const float* sop = &SO[(size_t)b * 256 * 512 + d];
        for (int s0 = 0; s0 < 256; s0 += 4) {
            float so[4];
            #pragma unroll
            for (int u = 0; u < 4; ++u) so[u] = sop[(s0 + u) * 512];
            #pragma unroll
            for (int u = 0; u < 4; ++u) c = fmaf(wlI[s0 + u], so[u], c);
        }
        out_cint[(size_t)b * 512 + d] = c;
    }
}

extern "C" void kernel_launch(void* const* d_in, const int* in_sizes, int n_in,
                              void* d_out, int out_size, void* d_ws, size_t ws_size,
                              hipStream_t stream) {
    const float* SO  = (const float*)d_in[0];
    const float* FS  = (const float*)d_in[1];
    const float* IV  = (const float*)d_in[2];
    const float* Wih = (const float*)d_in[3];
    const float* bih = (const float*)d_in[4];
    const float* Wii = (const float*)d_in[5];
    const float* bii = (const float*)d_in[6];
    const float* SV  = (const float*)d_in[7];
    const float* Wsh = (const float*)d_in[8];
    const float* bsh = (const float*)d_in[9];
    const float* Wsi = (const float*)d_in[10];
    const float* bsi = (const float*)d_in[11];

    float* ws    = (float*)d_ws;
    float* EhT   = ws;                 // [8][512][256]  exp2'd   1,048,576 f
    float* Es    = ws + 1048576;       // [2048][512]    exp2'd   1,048,576 f
    float* ii    = ws + 2097152;       // [8][512]                4,096 f
    float* ipart = ws + 2101248;       // [16][2048]              32,768 f
    ushort* Ast  = (ushort*)(ws + 2134016);  // [2048][1024] bf16
    ushort* Wt   = (ushort*)(ws + 3182592);  // [1536][1024] bf16
    const size_t NEED = (size_t)3969024 * 4;

    float* out_cslot = (float*)d_out;
    float* out_cint  = out_cslot + BB * TT * DD;

    if (ws_size >= NEED) {
        prep<<<1808, 256, 0, stream>>>(SO, Ast, Wsh, Wsi, Wih, Wt, FS, Wii, bii, ii);
        gemm_mfma<<<dim3(32, 24), 256, 0, stream>>>(Ast, Wt, bsh, bsi, bih, ii, IV,
                                                    EhT, Es, ipart);
        k3_fused<<<520, 512, 0, stream>>>(SO, EhT, Es, SV, ipart, out_cslot, out_cint, 16);
    } else {
        k0_ii<<<dim3(BB, 2), 256, 0, stream>>>(FS, Wii, bii, ii);
        k1_gemm_old<<<dim3(32, 8, 3), 256, 0, stream>>>(SO, Wsh, bsh, Wsi, bsi, Wih, bih,
                                                        ii, IV, EhT, Es, ipart);
        k3_fused<<<520, 512, 0, stream>>>(SO, EhT, Es, SV, ipart, out_cslot, out_cint, 8);
    }
}